// Round 3
// baseline (401.756 us; speedup 1.0000x reference)
//
#include <hip/hip_runtime.h>

#define NN 262144
#define RANK 16
#define NNZ_K 1310720

struct P8 { const float* p[8]; };

// ---------------------------------------------------------------------------
// K1: per-chunk partials  part[l][c][r] = sum_{j in chunk c} v_l[j][r]*z[j]
// chunk = 512 elements; 512 chunks. No atomics — K1b reduces.
// ---------------------------------------------------------------------------
__global__ __launch_bounds__(256) void k_levels_t(P8 v, const float* __restrict__ z,
                                                  float* __restrict__ part) {
    __shared__ float zl[512];
    __shared__ float red[8][4][16];
    const int tid  = threadIdx.x;
    const int base = blockIdx.x * 512;

    zl[tid]       = z[base + tid];
    zl[tid + 256] = z[base + tid + 256];
    __syncthreads();

    const int q = tid & 3;      // rank quad
    const int e = tid >> 2;     // element-in-group 0..63

    float4 acc[8];
#pragma unroll
    for (int l = 0; l < 8; ++l) acc[l] = make_float4(0.f, 0.f, 0.f, 0.f);

#pragma unroll
    for (int it = 0; it < 8; ++it) {
        const int jloc = it * 64 + e;
        const size_t j = (size_t)(base + jloc);
        const float zz = zl[jloc];
#pragma unroll
        for (int l = 0; l < 8; ++l) {
            const float4 vv = *(const float4*)(v.p[l] + j * RANK + q * 4);
            acc[l].x += vv.x * zz;
            acc[l].y += vv.y * zz;
            acc[l].z += vv.z * zz;
            acc[l].w += vv.w * zz;
        }
    }

    const int lane = tid & 63;
    const int wv   = tid >> 6;
#pragma unroll
    for (int l = 0; l < 8; ++l) {
        float4 a = acc[l];
#pragma unroll
        for (int m = 4; m <= 32; m <<= 1) {
            a.x += __shfl_xor(a.x, m);
            a.y += __shfl_xor(a.y, m);
            a.z += __shfl_xor(a.z, m);
            a.w += __shfl_xor(a.w, m);
        }
        if (lane < 4) *(float4*)&red[l][wv][lane * 4] = a;
    }
    __syncthreads();

    if (tid < 128) {
        const int l = tid >> 4;
        const int r = tid & 15;
        const float s = red[l][0][r] + red[l][1][r] + red[l][2][r] + red[l][3][r];
        part[(l * 512 + blockIdx.x) * 16 + r] = s;
    }
}

// ---------------------------------------------------------------------------
// K1b: tg[(l,h)][r] = sum over chunks c in half h of part[l][c][r]
// one block per (l,h) pair; 510 pairs. Also zeroes the loss accumulator.
// ---------------------------------------------------------------------------
__global__ __launch_bounds__(64) void k_reduce_t(const float* __restrict__ part,
                                                 float* __restrict__ tg,
                                                 float* __restrict__ loss) {
    const int b = blockIdx.x;
    if (b == 0 && threadIdx.x == 0) loss[0] = 0.f;
    const int t = b + 2;
    const int l = 30 - __clz(t);          // level 0..7
    const int h = t - (2 << l);           // half index at level l
    const int cnt = 256 >> l;             // chunks per half
    const int c0  = h * cnt;
    const int r = threadIdx.x & 15;
    const int g = threadIdx.x >> 4;

    float s = 0.f;
    for (int c = c0 + g; c < c0 + cnt; c += 4)
        s += part[(l * 512 + c) * 16 + r];

    __shared__ float red[64];
    red[threadIdx.x] = s;
    __syncthreads();
    if (threadIdx.x < 16)
        tg[((2 << l) - 2 + h) * 16 + r] = red[r] + red[16 + r] + red[32 + r] + red[48 + r];
}

// ---------------------------------------------------------------------------
// K2: w[i] = [L (L^T x)]_i + 1e-4*x[i] + sum_l u_l[i][:] . t_{l, sibling}
// Also zeroes y[i] for the spmv pass.
// ---------------------------------------------------------------------------
__global__ __launch_bounds__(256) void k_apply(const float* __restrict__ leaf, P8 u,
                                               const float* __restrict__ z,
                                               const float* __restrict__ tg,
                                               float* __restrict__ w,
                                               float* __restrict__ y) {
    __shared__ float Lp[8 * 1056];   // 8 blocks of 32x33
    __shared__ float xl[256];
    __shared__ float t32[8][32];
    __shared__ float tl[8][16];

    const int tid  = threadIdx.x;
    const int base = blockIdx.x * 256;

    const float4* Lg = (const float4*)(leaf + (size_t)base * 32);
#pragma unroll
    for (int k = 0; k < 8; ++k) {
        const int fi = tid + k * 256;          // 0..2047
        const float4 val = Lg[fi];
        const int lb  = fi >> 8;
        const int off = (fi & 255) * 4;
        const int row = off >> 5;
        const int col = off & 31;
        float* d = &Lp[lb * 1056 + row * 33 + col];
        d[0] = val.x; d[1] = val.y; d[2] = val.z; d[3] = val.w;
    }
    xl[tid] = z[base + tid];
    if (tid < 128) {
        const int l = tid >> 4;
        const int r = tid & 15;
        const int h = base >> (17 - l);
        tl[l][r] = tg[(((2 << l) - 2) + (h ^ 1)) * 16 + r];   // sibling half
    }
    __syncthreads();

    {
        const int lb = tid >> 5;
        const int c  = tid & 31;
        const float* Lb = &Lp[lb * 1056];
        const float* xb = &xl[lb * 32];
        float s = 0.f;
#pragma unroll
        for (int row = 0; row < 32; ++row)
            s += Lb[row * 33 + c] * xb[row];
        t32[lb][c] = s;
    }
    __syncthreads();

    {
        const int lb = tid >> 5;
        const int r  = tid & 31;
        const float* Lb = &Lp[lb * 1056 + r * 33];
        float acc = 1e-4f * xl[tid];
#pragma unroll
        for (int c = 0; c < 32; ++c)
            acc += Lb[c] * t32[lb][c];

        const size_t i = (size_t)(base + tid);
#pragma unroll
        for (int l = 0; l < 8; ++l) {
            const float4* up = (const float4*)(u.p[l] + i * RANK);
            const float4 a0 = up[0], a1 = up[1], a2 = up[2], a3 = up[3];
            acc += a0.x * tl[l][0]  + a0.y * tl[l][1]  + a0.z * tl[l][2]  + a0.w * tl[l][3]
                 + a1.x * tl[l][4]  + a1.y * tl[l][5]  + a1.z * tl[l][6]  + a1.w * tl[l][7]
                 + a2.x * tl[l][8]  + a2.y * tl[l][9]  + a2.z * tl[l][10] + a2.w * tl[l][11]
                 + a3.x * tl[l][12] + a3.y * tl[l][13] + a3.z * tl[l][14] + a3.w * tl[l][15];
        }
        w[i] = acc;
        y[i] = 0.f;
    }
}

// ---------------------------------------------------------------------------
// K3: y[rows[k]] += vals[k] * w[cols[k]], 4 nnz per thread, int4/float4 loads
// (indices are int32 on device — harness converts integer inputs to int32)
// ---------------------------------------------------------------------------
__global__ __launch_bounds__(256) void k_spmv(const int* __restrict__ idx,
                                              const float* __restrict__ vals,
                                              const float* __restrict__ w,
                                              float* __restrict__ y) {
    const int k = (blockIdx.x * 256 + threadIdx.x) * 4;
    const int4   r4 = *(const int4*)(idx + k);
    const int4   c4 = *(const int4*)(idx + NNZ_K + k);
    const float4 v4 = *(const float4*)(vals + k);
    atomicAdd(&y[r4.x], v4.x * w[c4.x]);
    atomicAdd(&y[r4.y], v4.y * w[c4.y]);
    atomicAdd(&y[r4.z], v4.z * w[c4.z]);
    atomicAdd(&y[r4.w], v4.w * w[c4.w]);
}

// ---------------------------------------------------------------------------
// K4: sum((y - z)^2) -> loss accumulator (zeroed by k_reduce_t), float4 loads
// ---------------------------------------------------------------------------
__global__ __launch_bounds__(256) void k_loss(const float* __restrict__ y,
                                              const float* __restrict__ z,
                                              float* __restrict__ loss) {
    const int i = blockIdx.x * 256 + threadIdx.x;
    const float4 a = ((const float4*)y)[i];
    const float4 b = ((const float4*)z)[i];
    const float dx = a.x - b.x, dy = a.y - b.y, dz = a.z - b.z, dw = a.w - b.w;
    float s = dx * dx + dy * dy + dz * dz + dw * dw;
#pragma unroll
    for (int m = 32; m >= 1; m >>= 1) s += __shfl_down(s, m);
    __shared__ float r4[4];
    const int lane = threadIdx.x & 63, wv = threadIdx.x >> 6;
    if (lane == 0) r4[wv] = s;
    __syncthreads();
    if (threadIdx.x == 0) atomicAdd(loss, r4[0] + r4[1] + r4[2] + r4[3]);
}

__global__ void k_fin(const float* __restrict__ loss, float* __restrict__ out) {
    out[0] = loss[0] * (1.0f / (float)NN);
}

// ---------------------------------------------------------------------------
extern "C" void kernel_launch(void* const* d_in, const int* in_sizes, int n_in,
                              void* d_out, int out_size, void* d_ws, size_t ws_size,
                              hipStream_t stream) {
    const float* leaf = (const float*)d_in[0];
    P8 u, v;
    for (int l = 0; l < 8; ++l) {
        u.p[l] = (const float*)d_in[1 + 2 * l];
        v.p[l] = (const float*)d_in[2 + 2 * l];
    }
    const int*   Aidx  = (const int*)d_in[17];
    const float* Avals = (const float*)d_in[18];
    const float* z     = (const float*)d_in[19];

    float* ws   = (float*)d_ws;
    float* part = ws;                  // 8*512*16 = 65536 floats
    float* tg   = ws + 65536;          // 8160 used (8192 reserved)
    float* loss = ws + 73728;          // 1 float
    float* y    = ws + 81920;          // N floats
    float* w    = ws + 81920 + NN;     // N floats

    k_levels_t<<<NN / 512, 256, 0, stream>>>(v, z, part);
    k_reduce_t<<<510, 64, 0, stream>>>(part, tg, loss);
    k_apply  <<<NN / 256, 256, 0, stream>>>(leaf, u, z, tg, w, y);
    k_spmv   <<<NNZ_K / 1024, 256, 0, stream>>>(Aidx, Avals, w, y);
    k_loss   <<<NN / 1024, 256, 0, stream>>>(y, z, loss);
    k_fin    <<<1, 1, 0, stream>>>(loss, (float*)d_out);
}

// Round 4
// 353.666 us; speedup vs baseline: 1.1360x; 1.1360x over previous
//
#include <hip/hip_runtime.h>

#define NN 262144
#define RANK 16
#define NNZ_K 1310720
#define NB 640           // k_bin blocks
#define BPB 2048         // nnz per k_bin block
#define NBKT 256         // row buckets (1024 rows each)
#define RPB 1024         // rows per bucket

struct P8 { const float* p[8]; };

// ---------------------------------------------------------------------------
// K1: per-chunk partials  part[l][c][r] = sum_{j in chunk c} v_l[j][r]*z[j]
// ---------------------------------------------------------------------------
__global__ __launch_bounds__(256) void k_levels_t(P8 v, const float* __restrict__ z,
                                                  float* __restrict__ part) {
    __shared__ float zl[512];
    __shared__ float red[8][4][16];
    const int tid  = threadIdx.x;
    const int base = blockIdx.x * 512;

    zl[tid]       = z[base + tid];
    zl[tid + 256] = z[base + tid + 256];
    __syncthreads();

    const int q = tid & 3;
    const int e = tid >> 2;

    float4 acc[8];
#pragma unroll
    for (int l = 0; l < 8; ++l) acc[l] = make_float4(0.f, 0.f, 0.f, 0.f);

#pragma unroll
    for (int it = 0; it < 8; ++it) {
        const int jloc = it * 64 + e;
        const size_t j = (size_t)(base + jloc);
        const float zz = zl[jloc];
#pragma unroll
        for (int l = 0; l < 8; ++l) {
            const float4 vv = *(const float4*)(v.p[l] + j * RANK + q * 4);
            acc[l].x += vv.x * zz;
            acc[l].y += vv.y * zz;
            acc[l].z += vv.z * zz;
            acc[l].w += vv.w * zz;
        }
    }

    const int lane = tid & 63;
    const int wv   = tid >> 6;
#pragma unroll
    for (int l = 0; l < 8; ++l) {
        float4 a = acc[l];
#pragma unroll
        for (int m = 4; m <= 32; m <<= 1) {
            a.x += __shfl_xor(a.x, m);
            a.y += __shfl_xor(a.y, m);
            a.z += __shfl_xor(a.z, m);
            a.w += __shfl_xor(a.w, m);
        }
        if (lane < 4) *(float4*)&red[l][wv][lane * 4] = a;
    }
    __syncthreads();

    if (tid < 128) {
        const int l = tid >> 4;
        const int r = tid & 15;
        const float s = red[l][0][r] + red[l][1][r] + red[l][2][r] + red[l][3][r];
        part[(l * 512 + blockIdx.x) * 16 + r] = s;
    }
}

// ---------------------------------------------------------------------------
// K1b: tg[(l,h)][r] = sum of partials; one block per (l,h). Zeroes loss.
// ---------------------------------------------------------------------------
__global__ __launch_bounds__(64) void k_reduce_t(const float* __restrict__ part,
                                                 float* __restrict__ tg,
                                                 float* __restrict__ loss) {
    const int b = blockIdx.x;
    if (b == 0 && threadIdx.x == 0) loss[0] = 0.f;
    const int t = b + 2;
    const int l = 30 - __clz(t);
    const int h = t - (2 << l);
    const int cnt = 256 >> l;
    const int c0  = h * cnt;
    const int r = threadIdx.x & 15;
    const int g = threadIdx.x >> 4;

    float s = 0.f;
    for (int c = c0 + g; c < c0 + cnt; c += 4)
        s += part[(l * 512 + c) * 16 + r];

    __shared__ float red[64];
    red[threadIdx.x] = s;
    __syncthreads();
    if (threadIdx.x < 16)
        tg[((2 << l) - 2 + h) * 16 + r] = red[r] + red[16 + r] + red[32 + r] + red[48 + r];
}

// ---------------------------------------------------------------------------
// K2: w[i] = [L (L^T x)]_i + 1e-4*x[i] + sum_l u_l[i][:] . t_{l, sibling}
// y-zeroing only used in the fallback path (y may be null).
// ---------------------------------------------------------------------------
__global__ __launch_bounds__(256) void k_apply(const float* __restrict__ leaf, P8 u,
                                               const float* __restrict__ z,
                                               const float* __restrict__ tg,
                                               float* __restrict__ w,
                                               float* __restrict__ y) {
    __shared__ float Lp[8 * 1056];
    __shared__ float xl[256];
    __shared__ float t32[8][32];
    __shared__ float tl[8][16];

    const int tid  = threadIdx.x;
    const int base = blockIdx.x * 256;

    const float4* Lg = (const float4*)(leaf + (size_t)base * 32);
#pragma unroll
    for (int k = 0; k < 8; ++k) {
        const int fi = tid + k * 256;
        const float4 val = Lg[fi];
        const int lb  = fi >> 8;
        const int off = (fi & 255) * 4;
        const int row = off >> 5;
        const int col = off & 31;
        float* d = &Lp[lb * 1056 + row * 33 + col];
        d[0] = val.x; d[1] = val.y; d[2] = val.z; d[3] = val.w;
    }
    xl[tid] = z[base + tid];
    if (tid < 128) {
        const int l = tid >> 4;
        const int r = tid & 15;
        const int h = base >> (17 - l);
        tl[l][r] = tg[(((2 << l) - 2) + (h ^ 1)) * 16 + r];
    }
    __syncthreads();

    {
        const int lb = tid >> 5;
        const int c  = tid & 31;
        const float* Lb = &Lp[lb * 1056];
        const float* xb = &xl[lb * 32];
        float s = 0.f;
#pragma unroll
        for (int row = 0; row < 32; ++row)
            s += Lb[row * 33 + c] * xb[row];
        t32[lb][c] = s;
    }
    __syncthreads();

    {
        const int lb = tid >> 5;
        const int r  = tid & 31;
        const float* Lb = &Lp[lb * 1056 + r * 33];
        float acc = 1e-4f * xl[tid];
#pragma unroll
        for (int c = 0; c < 32; ++c)
            acc += Lb[c] * t32[lb][c];

        const size_t i = (size_t)(base + tid);
#pragma unroll
        for (int l = 0; l < 8; ++l) {
            const float4* up = (const float4*)(u.p[l] + i * RANK);
            const float4 a0 = up[0], a1 = up[1], a2 = up[2], a3 = up[3];
            acc += a0.x * tl[l][0]  + a0.y * tl[l][1]  + a0.z * tl[l][2]  + a0.w * tl[l][3]
                 + a1.x * tl[l][4]  + a1.y * tl[l][5]  + a1.z * tl[l][6]  + a1.w * tl[l][7]
                 + a2.x * tl[l][8]  + a2.y * tl[l][9]  + a2.z * tl[l][10] + a2.w * tl[l][11]
                 + a3.x * tl[l][12] + a3.y * tl[l][13] + a3.z * tl[l][14] + a3.w * tl[l][15];
        }
        w[i] = acc;
        if (y) y[i] = 0.f;
    }
}

// ---------------------------------------------------------------------------
// K3a: bucket-sort (row, val*w[col]) pairs. Zero global atomics.
// Block bl handles BPB nnz; output block-contiguous, bucket-sorted within
// block; per-(bucket,block) descriptor gdesc[b*NB+bl] = start | (count<<16).
// ---------------------------------------------------------------------------
__global__ __launch_bounds__(256) void k_bin(const int* __restrict__ idx,
                                             const float* __restrict__ vals,
                                             const float* __restrict__ w,
                                             unsigned long long* __restrict__ gpairs,
                                             int* __restrict__ gdesc) {
    __shared__ unsigned long long pairs[BPB];   // 16 KB
    __shared__ int hist[NBKT];
    __shared__ int scan[NBKT];
    __shared__ int cursor[NBKT];

    const int t  = threadIdx.x;
    const int bl = blockIdx.x;
    const int base = bl * BPB;

    hist[t] = 0;
    __syncthreads();

    int   rows[8];
    float pv[8];
#pragma unroll
    for (int i = 0; i < 2; ++i) {
        const int k = base + i * 1024 + t * 4;
        const int4   r4 = *(const int4*)(idx + k);
        const int4   c4 = *(const int4*)(idx + NNZ_K + k);
        const float4 v4 = *(const float4*)(vals + k);
        rows[i*4+0] = r4.x; pv[i*4+0] = v4.x * w[c4.x];
        rows[i*4+1] = r4.y; pv[i*4+1] = v4.y * w[c4.y];
        rows[i*4+2] = r4.z; pv[i*4+2] = v4.z * w[c4.z];
        rows[i*4+3] = r4.w; pv[i*4+3] = v4.w * w[c4.w];
        atomicAdd(&hist[r4.x >> 10], 1);
        atomicAdd(&hist[r4.y >> 10], 1);
        atomicAdd(&hist[r4.z >> 10], 1);
        atomicAdd(&hist[r4.w >> 10], 1);
    }
    __syncthreads();

    // inclusive Hillis-Steele scan over 256 buckets
    const int cnt = hist[t];
    scan[t] = cnt;
    __syncthreads();
    for (int off = 1; off < NBKT; off <<= 1) {
        const int add = (t >= off) ? scan[t - off] : 0;
        __syncthreads();
        scan[t] += add;
        __syncthreads();
    }
    const int st = scan[t] - cnt;          // exclusive start
    gdesc[t * NB + bl] = st | (cnt << 16); // transposed: coalesced read in k_accum
    cursor[t] = st;
    __syncthreads();

#pragma unroll
    for (int i = 0; i < 8; ++i) {
        const int b   = rows[i] >> 10;
        const int pos = atomicAdd(&cursor[b], 1);
        pairs[pos] = ((unsigned long long)__float_as_uint(pv[i]) << 32) | (unsigned)rows[i];
    }
    __syncthreads();

    // fully-coalesced block-contiguous write-out (16 B per thread per iter)
    const ulonglong2* ps = (const ulonglong2*)pairs;
    ulonglong2*       pd = (ulonglong2*)(gpairs + (size_t)bl * BPB);
#pragma unroll
    for (int i = 0; i < 4; ++i)
        pd[i * 256 + t] = ps[i * 256 + t];
}

// ---------------------------------------------------------------------------
// K3b: block b accumulates its 1024 rows in LDS from all NB segments, then
// computes sum((y-z)^2) for those rows directly. No global y.
// ---------------------------------------------------------------------------
__global__ __launch_bounds__(512) void k_accum(const unsigned long long* __restrict__ gpairs,
                                               const int* __restrict__ gdesc,
                                               const float* __restrict__ z,
                                               float* __restrict__ loss) {
    __shared__ float acc[RPB];
    __shared__ float red[8];
    const int t = threadIdx.x;
    const int b = blockIdx.x;
    acc[t] = 0.f;
    acc[t + 512] = 0.f;
    __syncthreads();

    for (int bl = t; bl < NB; bl += 512) {
        const int d  = gdesc[b * NB + bl];
        const int st = d & 0xffff;
        const int c  = d >> 16;
        const unsigned long long* p = gpairs + (size_t)bl * BPB + st;
        for (int j = 0; j < c; ++j) {
            const unsigned long long pr = p[j];
            atomicAdd(&acc[(int)(pr & 1023u)], __uint_as_float((unsigned)(pr >> 32)));
        }
    }
    __syncthreads();

    float s = 0.f;
#pragma unroll
    for (int i = 0; i < 2; ++i) {
        const int r = i * 512 + t;
        const float d = acc[r] - z[b * RPB + r];
        s += d * d;
    }
#pragma unroll
    for (int m = 32; m >= 1; m >>= 1) s += __shfl_down(s, m);
    if ((t & 63) == 0) red[t >> 6] = s;
    __syncthreads();
    if (t == 0) {
        float tt = 0.f;
#pragma unroll
        for (int i = 0; i < 8; ++i) tt += red[i];
        atomicAdd(loss, tt);
    }
}

// --------------------------- fallback path (small ws) ----------------------
__global__ __launch_bounds__(256) void k_spmv(const int* __restrict__ idx,
                                              const float* __restrict__ vals,
                                              const float* __restrict__ w,
                                              float* __restrict__ y) {
    const int k = (blockIdx.x * 256 + threadIdx.x) * 4;
    const int4   r4 = *(const int4*)(idx + k);
    const int4   c4 = *(const int4*)(idx + NNZ_K + k);
    const float4 v4 = *(const float4*)(vals + k);
    atomicAdd(&y[r4.x], v4.x * w[c4.x]);
    atomicAdd(&y[r4.y], v4.y * w[c4.y]);
    atomicAdd(&y[r4.z], v4.z * w[c4.z]);
    atomicAdd(&y[r4.w], v4.w * w[c4.w]);
}

__global__ __launch_bounds__(256) void k_loss(const float* __restrict__ y,
                                              const float* __restrict__ z,
                                              float* __restrict__ loss) {
    const int i = blockIdx.x * 256 + threadIdx.x;
    const float4 a = ((const float4*)y)[i];
    const float4 b = ((const float4*)z)[i];
    const float dx = a.x - b.x, dy = a.y - b.y, dz = a.z - b.z, dw = a.w - b.w;
    float s = dx * dx + dy * dy + dz * dz + dw * dw;
#pragma unroll
    for (int m = 32; m >= 1; m >>= 1) s += __shfl_down(s, m);
    __shared__ float r4s[4];
    const int lane = threadIdx.x & 63, wv = threadIdx.x >> 6;
    if (lane == 0) r4s[wv] = s;
    __syncthreads();
    if (threadIdx.x == 0) atomicAdd(loss, r4s[0] + r4s[1] + r4s[2] + r4s[3]);
}

__global__ void k_fin(const float* __restrict__ loss, float* __restrict__ out) {
    out[0] = loss[0] * (1.0f / (float)NN);
}

// ---------------------------------------------------------------------------
extern "C" void kernel_launch(void* const* d_in, const int* in_sizes, int n_in,
                              void* d_out, int out_size, void* d_ws, size_t ws_size,
                              hipStream_t stream) {
    const float* leaf = (const float*)d_in[0];
    P8 u, v;
    for (int l = 0; l < 8; ++l) {
        u.p[l] = (const float*)d_in[1 + 2 * l];
        v.p[l] = (const float*)d_in[2 + 2 * l];
    }
    const int*   Aidx  = (const int*)d_in[17];
    const float* Avals = (const float*)d_in[18];
    const float* z     = (const float*)d_in[19];

    float* ws   = (float*)d_ws;
    // layout (floats):
    float* part  = ws;                     // 65536
    float* tg    = ws + 65536;             // 8192
    float* loss  = ws + 73728;             // 1 (+pad to 73792)
    float* w     = ws + 73792;             // 262144 -> end 335936
    int*   gdesc = (int*)(ws + 335936);    // NBKT*NB = 163840 -> end 499776
    unsigned long long* gpairs = (unsigned long long*)(ws + 499776); // NB*BPB*8B
    const size_t need_main = (size_t)(499776 + (size_t)NB * BPB * 2) * 4;

    k_levels_t<<<NN / 512, 256, 0, stream>>>(v, z, part);
    k_reduce_t<<<510, 64, 0, stream>>>(part, tg, loss);

    if (ws_size >= need_main) {
        k_apply<<<NN / 256, 256, 0, stream>>>(leaf, u, z, tg, w, nullptr);
        k_bin  <<<NB, 256, 0, stream>>>(Aidx, Avals, w, gpairs, gdesc);
        k_accum<<<NBKT, 512, 0, stream>>>(gpairs, gdesc, z, loss);
    } else {
        float* y = ws + 335936;            // fallback: y where desc/pairs were
        k_apply<<<NN / 256, 256, 0, stream>>>(leaf, u, z, tg, w, y);
        k_spmv <<<NNZ_K / 1024, 256, 0, stream>>>(Aidx, Avals, w, y);
        k_loss <<<NN / 1024, 256, 0, stream>>>(y, z, loss);
    }
    k_fin<<<1, 1, 0, stream>>>(loss, (float*)d_out);
}